// Round 16
// baseline (26.682 us; speedup 1.0000x reference)
//
#include <hip/hip_runtime.h>

// out[b,h] = (X X^T) X == X (X^T X) per head; X = x[b,h] : [2048 x 64] fp32.
// MFMA bf16 (fp32 accumulate), 2 dispatches + 2KB memset:
//  K1 (512 blocks x 256 thr, 128-row chunks): global->reg (8 rows x 4 cols),
//     f2bf, transpose via ds_write_b128 into swizzled XT; 16 MFMA/wave Gram
//     (K=128); packed bf16 partial stored sc0sc1 (coherent point, cross-XCD
//     safe); vmcnt0 + per-head counter; the 16th arriver alone reduces all 16
//     partials (sc loads, fixed order) -> pre-swizzled bf16 G image (plain
//     stores; kernel boundary publishes). No block ever spins.
//  K2b (512 blocks x 512 thr, 128-row tiles): reg-stage f32 X + DMA G;
//     one barrier; 8 MFMA/wave; out.  (identical to R15)
// C/D layout per m89: col = lane&15, row = (lane>>4)*4 + reg.

#define TDIM 2048
#define DDIM 64
#define NHEADS 32
#define NCH 16                                    // 128-row chunks per head

typedef float f4 __attribute__((ext_vector_type(4)));
typedef float f32x4 __attribute__((ext_vector_type(4)));
typedef short bf16x8 __attribute__((ext_vector_type(8)));
typedef short s4 __attribute__((ext_vector_type(4)));
typedef int i2 __attribute__((ext_vector_type(2)));

// Async global->LDS DMA, 16 B/lane. LDS dest wave-uniform; lane l -> dest+l*16.
__device__ __forceinline__ void async_copy16(const void* g, void* l) {
    __builtin_amdgcn_global_load_lds(
        (const __attribute__((address_space(1))) void*)g,
        (__attribute__((address_space(3))) void*)l, 16, 0, 0);
}

// f32 -> bf16 bits (RNE) and back.
__device__ __forceinline__ short f2bf(float f) {
    unsigned u = __builtin_bit_cast(unsigned, f);
    unsigned r = (u + 0x7fffu + ((u >> 16) & 1u)) >> 16;
    return (short)r;
}
__device__ __forceinline__ float bf2f(short s) {
    return __builtin_bit_cast(float, ((unsigned)(unsigned short)s) << 16);
}

// Coherent-point 8 B store / 8x8 B batched loads (sc0 sc1).
__device__ __forceinline__ void st8_cc(void* p, i2 v) {
    asm volatile("global_store_dwordx2 %0, %1, off sc0 sc1"
                 :: "v"(p), "v"(v) : "memory");
}
__device__ __forceinline__ void ld8x2_cc(const short* p0, const short* p1,
                                         const short* p2, const short* p3,
                                         const short* p4, const short* p5,
                                         const short* p6, const short* p7,
                                         i2& v0, i2& v1, i2& v2, i2& v3,
                                         i2& v4, i2& v5, i2& v6, i2& v7) {
    asm volatile(
        "global_load_dwordx2 %0, %8, off sc0 sc1\n\t"
        "global_load_dwordx2 %1, %9, off sc0 sc1\n\t"
        "global_load_dwordx2 %2, %10, off sc0 sc1\n\t"
        "global_load_dwordx2 %3, %11, off sc0 sc1\n\t"
        "global_load_dwordx2 %4, %12, off sc0 sc1\n\t"
        "global_load_dwordx2 %5, %13, off sc0 sc1\n\t"
        "global_load_dwordx2 %6, %14, off sc0 sc1\n\t"
        "global_load_dwordx2 %7, %15, off sc0 sc1\n\t"
        "s_waitcnt vmcnt(0)"
        : "=&v"(v0), "=&v"(v1), "=&v"(v2), "=&v"(v3),
          "=&v"(v4), "=&v"(v5), "=&v"(v6), "=&v"(v7)
        : "v"(p0), "v"(p1), "v"(p2), "v"(p3),
          "v"(p4), "v"(p5), "v"(p6), "v"(p7)
        : "memory");
}

// Swizzled fragment pointer: row-major bf16 tile (rowlen shorts/row); byte
// offset within row = (kelem*2) ^ ((row&7)<<4). 16 B alignment preserved.
__device__ __forceinline__ const bf16x8* fragp(const short* base, int row,
                                               int rowlen, int kelem) {
    const char* p = (const char*)(base + row * rowlen);
    return (const bf16x8*)(p + ((kelem * 2) ^ ((row & 7) << 4)));
}

// ---------------- K1: partial Gram + last-arriver reduce ----------------
__global__ __launch_bounds__(256) void k1_gram(const float* __restrict__ x,
                                               short* __restrict__ part,
                                               short* __restrict__ gbf,
                                               unsigned* __restrict__ syncw) {
    __shared__ __align__(16) short XT[64 * 128];  // 16 KB transposed swz bf16
    __shared__ int is_last;

    const int b    = blockIdx.x;        // 0..511
    const int tid  = threadIdx.x;
    const int lane = tid & 63;
    const int w    = tid >> 6;
    const int head = b >> 4, ch = b & 15;

    const float* xh = x + ((size_t)head * TDIM + ch * 128) * DDIM;

    // Thread owns rows r0..r0+7 x cols c4..c4+3.
    const int rg = tid >> 4, cg = tid & 15;
    const int r0 = rg * 8, c4 = cg * 4;

    f4 v[8];
#pragma unroll
    for (int k = 0; k < 8; ++k)
        v[k] = *reinterpret_cast<const f4*>(xh + (size_t)(r0 + k) * DDIM + c4);

    // Transpose: one b128 (8 t-contiguous bf16) per column.
#pragma unroll
    for (int j = 0; j < 4; ++j) {
        bf16x8 pk;
#pragma unroll
        for (int k = 0; k < 8; ++k) pk[k] = f2bf(v[k][j]);
        const int c = c4 + j;
        *(bf16x8*)((char*)XT + c * 256 + ((2 * r0) ^ ((c & 7) << 4))) = pk;
    }
    __syncthreads();

    // Gram MFMA over K=128: wave w owns 2x2 quad of 16x16 G tiles.
    const int li = lane & 15, g = lane >> 4;
    const int iq0 = (w >> 1) * 2, jq0 = (w & 1) * 2;

    f32x4 acc[2][2];
#pragma unroll
    for (int a = 0; a < 2; ++a)
#pragma unroll
        for (int q = 0; q < 2; ++q) acc[a][q] = (f32x4){0.f, 0.f, 0.f, 0.f};

#pragma unroll
    for (int k0 = 0; k0 < 128; k0 += 32) {
        bf16x8 af[2], bv[2];
        af[0] = *fragp(XT, (iq0 + 0) * 16 + li, 128, k0 + 8 * g);
        af[1] = *fragp(XT, (iq0 + 1) * 16 + li, 128, k0 + 8 * g);
        bv[0] = *fragp(XT, (jq0 + 0) * 16 + li, 128, k0 + 8 * g);
        bv[1] = *fragp(XT, (jq0 + 1) * 16 + li, 128, k0 + 8 * g);
#pragma unroll
        for (int a = 0; a < 2; ++a)
#pragma unroll
            for (int q = 0; q < 2; ++q)
                acc[a][q] = __builtin_amdgcn_mfma_f32_16x16x32_bf16(
                    af[a], bv[q], acc[a][q], 0, 0, 0);
    }

    // Packed bf16 partial store, sc0sc1: slot f = ((w*2+a)*2+d)*64 + lane.
    short* pp = part + (size_t)b * 4096;
#pragma unroll
    for (int a = 0; a < 2; ++a)
#pragma unroll
        for (int d = 0; d < 2; ++d) {
            s4 pk;
#pragma unroll
            for (int q = 0; q < 4; ++q) pk[q] = f2bf(acc[a][d][q]);
            st8_cc(pp + ((((w * 2 + a) * 2 + d) * 64 + lane) << 2),
                   __builtin_bit_cast(i2, pk));
        }
    asm volatile("s_waitcnt vmcnt(0)" ::: "memory");  // drain own sc stores
    __syncthreads();

    if (tid == 0) {
        unsigned old = __hip_atomic_fetch_add(&syncw[head * 64], 1u,
                                              __ATOMIC_RELAXED,
                                              __HIP_MEMORY_SCOPE_AGENT);
        is_last = (old == NCH - 1);
    }
    __syncthreads();
    if (!is_last) return;

    // Last arriver: reduce 16 partials (sc loads, fixed order) -> G image.
    const short* ph = part + (size_t)head * NCH * 4096;
    char* gb = (char*)gbf + (size_t)head * 8192;
#pragma unroll
    for (int s = 0; s < 4; ++s) {
        const int f = s * 256 + tid;            // s4-slot 0..1023
        const short* p0 = ph + (f << 2);
        i2 u[16];
        ld8x2_cc(p0,              p0 + 4096,      p0 + 2 * 4096,  p0 + 3 * 4096,
                 p0 + 4 * 4096,   p0 + 5 * 4096,  p0 + 6 * 4096,  p0 + 7 * 4096,
                 u[0], u[1], u[2], u[3], u[4], u[5], u[6], u[7]);
        ld8x2_cc(p0 + 8 * 4096,   p0 + 9 * 4096,  p0 + 10 * 4096, p0 + 11 * 4096,
                 p0 + 12 * 4096,  p0 + 13 * 4096, p0 + 14 * 4096, p0 + 15 * 4096,
                 u[8], u[9], u[10], u[11], u[12], u[13], u[14], u[15]);
        float sm[4] = {0.f, 0.f, 0.f, 0.f};
#pragma unroll
        for (int c = 0; c < 16; ++c) {          // fixed order: deterministic
            const s4 pv = __builtin_bit_cast(s4, u[c]);
#pragma unroll
            for (int q = 0; q < 4; ++q) sm[q] += bf2f(pv[q]);
        }
        // decode f = ((w*2+a)*2+d)*64+lane -> (i,j); plain swizzled store.
        const int ln = f & 63, wad = f >> 6;
        const int ww = wad >> 2, aa = (wad >> 1) & 1, dd = wad & 1;
        const int gg = ln >> 4, ll = ln & 15;
        const int j = ((ww & 1) * 2 + dd) * 16 + ll;
        const int ib = ((ww >> 1) * 2 + aa) * 16 + gg * 4;
#pragma unroll
        for (int q = 0; q < 4; ++q) {
            const int i = ib + q;
            *(short*)(gb + i * 128 + ((2 * j) ^ ((i & 7) << 4))) = f2bf(sm[q]);
        }
    }
}

// ---------------- K2b: out = X*G via MFMA (identical to R15) ----------------
__global__ __launch_bounds__(512) void k2b_xg(const float* __restrict__ x,
                                              float* __restrict__ out,
                                              const short* __restrict__ gbf) {
    __shared__ __align__(16) short Xb[8192];      // 16 KB bf16 swz (128x64)
    __shared__ __align__(16) short Gb[4096];      // 8 KB bf16 G swz

    const int b    = blockIdx.x;        // 0..511
    const int tid  = threadIdx.x;       // 0..511
    const int lane = tid & 63;
    const int w    = tid >> 6;          // 0..7
    const int head = b >> 4, ch = b & 15;

    {   // DMA bf16 G image (8 KB, linear; pre-swizzled at write time)
        const short* gg = gbf + (size_t)head * 4096 + w * 512 + lane * 8;
        async_copy16(gg, Gb + w * 512);
    }

    // Reg-stage X tile (128x64 f32), convert, swizzled LDS writes.
    const float* xh = x + ((size_t)head * TDIM + ch * 128) * DDIM;
#pragma unroll
    for (int e = 0; e < 4; ++e) {
        const int i4 = e * 512 + tid;            // f4 index in 128x64 tile
        const int r  = i4 >> 4;                  // 0..127
        const int c4 = (i4 & 15) << 2;
        const f4 v = *reinterpret_cast<const f4*>(xh + (size_t)i4 * 4);
        s4 pk;
        pk[0] = f2bf(v[0]); pk[1] = f2bf(v[1]);
        pk[2] = f2bf(v[2]); pk[3] = f2bf(v[3]);
        *(s4*)((char*)Xb + r * 128 + ((2 * c4) ^ ((r & 7) << 4))) = pk;
    }
    __syncthreads();   // drains G DMA (vmcnt) + Xb writes (lgkmcnt)

    // MFMA: wave w owns rows w*16..w*16+15 x 4 col-tiles, K=64.
    const int li = lane & 15, g = lane >> 4;

    f32x4 acc[4];
#pragma unroll
    for (int d = 0; d < 4; ++d) acc[d] = (f32x4){0.f, 0.f, 0.f, 0.f};

#pragma unroll
    for (int k0 = 0; k0 < 64; k0 += 32) {
        bf16x8 af, bv[4];
        af = *fragp(Xb, w * 16 + li, 64, k0 + 8 * g);
#pragma unroll
        for (int d = 0; d < 4; ++d)
            bv[d] = *fragp(Gb, d * 16 + li, 64, k0 + 8 * g);
#pragma unroll
        for (int d = 0; d < 4; ++d)
            acc[d] = __builtin_amdgcn_mfma_f32_16x16x32_bf16(
                af, bv[d], acc[d], 0, 0, 0);
    }

    float* oh = out + ((size_t)head * TDIM + ch * 128) * DDIM;
#pragma unroll
    for (int d = 0; d < 4; ++d)
#pragma unroll
        for (int q = 0; q < 4; ++q)
            oh[(w * 16 + g * 4 + q) * 64 + d * 16 + li] = acc[d][q];
}

extern "C" void kernel_launch(void* const* d_in, const int* in_sizes, int n_in,
                              void* d_out, int out_size, void* d_ws, size_t ws_size,
                              hipStream_t stream) {
    const float* x = (const float*)d_in[0];
    float* out  = (float*)d_out;
    short* part = (short*)d_ws;                          // 512*8 KB = 4.2 MB
    short* gbf  = part + (size_t)512 * 4096;             // 256 KB
    unsigned* syncw = (unsigned*)(gbf + (size_t)NHEADS * 4096);  // 8 KB

    (void)hipMemsetAsync(syncw, 0, 8192, stream);        // zero per-head counters
    k1_gram<<<NHEADS * NCH, 256, 0, stream>>>(x, part, gbf, syncw);
    k2b_xg<<<512, 512, 0, stream>>>(x, out, gbf);
}

// Round 17
// 18.847 us; speedup vs baseline: 1.4157x; 1.4157x over previous
//
#include <hip/hip_runtime.h>

// out[b,h] = (X X^T) X == X (X^T X) per head; X = x[b,h] : [2048 x 64] fp32.
// MFMA bf16 (fp32 accumulate), 3 dispatches (R15 skeleton; K1 at 512 thr):
//  K1 (512 blocks x 512 thr, 128-row chunks, 16 waves/CU): global->reg
//     (4 rows x 4 cols/thread), f2bf, transpose via b64 writes into swizzled
//     XT (16 KB); 8 MFMA/wave Gram (K=128); packed bf16 partial store.
//  K2a (128 blocks): fixed-order fp32 reduce of 16 bf16 partials -> G;
//     emits PRE-SWIZZLED bf16 G image (m173) for K2b's linear DMA.
//  K2b (512 blocks x 512 thr, 128-row tiles): reg-stage f32 X + DMA G
//     concurrently; one barrier; 8 MFMA/wave; out.  (identical to R15)
// C/D layout per m89: col = lane&15, row = (lane>>4)*4 + reg.

#define TDIM 2048
#define DDIM 64
#define NHEADS 32
#define NCH 16                                    // 128-row chunks per head

typedef float f4 __attribute__((ext_vector_type(4)));
typedef float f32x4 __attribute__((ext_vector_type(4)));
typedef short bf16x8 __attribute__((ext_vector_type(8)));
typedef short s4 __attribute__((ext_vector_type(4)));

// Async global->LDS DMA, 16 B/lane. LDS dest wave-uniform; lane l -> dest+l*16.
__device__ __forceinline__ void async_copy16(const void* g, void* l) {
    __builtin_amdgcn_global_load_lds(
        (const __attribute__((address_space(1))) void*)g,
        (__attribute__((address_space(3))) void*)l, 16, 0, 0);
}

// f32 -> bf16 bits (RNE) and back.
__device__ __forceinline__ short f2bf(float f) {
    unsigned u = __builtin_bit_cast(unsigned, f);
    unsigned r = (u + 0x7fffu + ((u >> 16) & 1u)) >> 16;
    return (short)r;
}
__device__ __forceinline__ float bf2f(short s) {
    return __builtin_bit_cast(float, ((unsigned)(unsigned short)s) << 16);
}

// Swizzled fragment pointer: row-major bf16 tile (rowlen shorts/row); byte
// offset within row = (kelem*2) ^ ((row&7)<<4). 16 B alignment preserved.
__device__ __forceinline__ const bf16x8* fragp(const short* base, int row,
                                               int rowlen, int kelem) {
    const char* p = (const char*)(base + row * rowlen);
    return (const bf16x8*)(p + ((kelem * 2) ^ ((row & 7) << 4)));
}

// ---------------- K1: partial Gram (512 threads, 128-row chunks) ------------
__global__ __launch_bounds__(512) void k1_gram(const float* __restrict__ x,
                                               short* __restrict__ part) {
    __shared__ __align__(16) short XT[64 * 128];  // 16 KB transposed swz bf16

    const int b    = blockIdx.x;        // 0..511
    const int tid  = threadIdx.x;       // 0..511
    const int lane = tid & 63;
    const int w    = tid >> 6;          // 0..7
    const int head = b >> 4, ch = b & 15;

    const float* xh = x + ((size_t)head * TDIM + ch * 128) * DDIM;

    // Thread owns rows r0..r0+3 x cols c4..c4+3.
    const int rg = tid >> 4;            // 0..31
    const int cg = tid & 15;
    const int r0 = rg * 4, c4 = cg * 4;

    f4 v[4];
#pragma unroll
    for (int k = 0; k < 4; ++k)
        v[k] = *reinterpret_cast<const f4*>(xh + (size_t)(r0 + k) * DDIM + c4);

    // Transpose: per column j, 4 t-contiguous bf16 as one b64 write.
#pragma unroll
    for (int j = 0; j < 4; ++j) {
        s4 t4;
#pragma unroll
        for (int k = 0; k < 4; ++k) t4[k] = f2bf(v[k][j]);
        const int c = c4 + j;
        *(s4*)((char*)XT + c * 256 + ((2 * r0) ^ ((c & 7) << 4))) = t4;
    }
    __syncthreads();

    // Gram MFMA over K=128: wave w owns i_tile = w>>1, j_tiles {(w&1)*2+d}.
    const int li = lane & 15, g = lane >> 4;
    const int i_tile = w >> 1, j0 = (w & 1) * 2;

    f32x4 acc[2];
#pragma unroll
    for (int d = 0; d < 2; ++d) acc[d] = (f32x4){0.f, 0.f, 0.f, 0.f};

#pragma unroll
    for (int k0 = 0; k0 < 128; k0 += 32) {
        bf16x8 af, bv[2];
        af = *fragp(XT, i_tile * 16 + li, 128, k0 + 8 * g);
        bv[0] = *fragp(XT, (j0 + 0) * 16 + li, 128, k0 + 8 * g);
        bv[1] = *fragp(XT, (j0 + 1) * 16 + li, 128, k0 + 8 * g);
#pragma unroll
        for (int d = 0; d < 2; ++d)
            acc[d] = __builtin_amdgcn_mfma_f32_16x16x32_bf16(
                af, bv[d], acc[d], 0, 0, 0);
    }

    // Packed bf16 partial store: s4 index f = (w*2+d)*64 + lane.
    short* pp = part + (size_t)b * 4096;
#pragma unroll
    for (int d = 0; d < 2; ++d) {
        s4 o;
#pragma unroll
        for (int q = 0; q < 4; ++q) o[q] = f2bf(acc[d][q]);
        *(s4*)(pp + (((w * 2 + d) * 64 + lane) << 2)) = o;
    }
}

// ---------------- K2a: reduce packed partials -> pre-swizzled bf16 G --------
__global__ __launch_bounds__(256) void k2a_reduce(const short* __restrict__ part,
                                                  short* __restrict__ gbf) {
    const int b    = blockIdx.x;        // 0..127
    const int tid  = threadIdx.x;
    const int head = b >> 2, quarter = b & 3;

    const int f = quarter * 256 + tid;  // s4 index within chunk, 0..1023
    const short* ph = part + (size_t)head * NCH * 4096 + (f << 2);

    float s[4] = {0.f, 0.f, 0.f, 0.f};
#pragma unroll
    for (int c = 0; c < NCH; ++c) {
        const s4 v = *reinterpret_cast<const s4*>(ph + (size_t)c * 4096);
#pragma unroll
        for (int q = 0; q < 4; ++q) s[q] += bf2f(v[q]);
    }

    // decode f = (w*2+d)*64+lane -> (i,j); store swizzled G image.
    const int lane = f & 63, wd = f >> 6;
    const int w = wd >> 1, d = wd & 1;
    const int g = lane >> 4, li = lane & 15;
    const int i_tile = w >> 1, j_tile = (w & 1) * 2 + d;
    const int j = j_tile * 16 + li;
    char* gb = (char*)gbf + (size_t)head * 8192;
#pragma unroll
    for (int q = 0; q < 4; ++q) {
        const int i = i_tile * 16 + g * 4 + q;
        *(short*)(gb + i * 128 + ((2 * j) ^ ((i & 7) << 4))) = f2bf(s[q]);
    }
}

// ---------------- K2b: out = X*G via MFMA (identical to R15) ----------------
__global__ __launch_bounds__(512) void k2b_xg(const float* __restrict__ x,
                                              float* __restrict__ out,
                                              const short* __restrict__ gbf) {
    __shared__ __align__(16) short Xb[8192];      // 16 KB bf16 swz (128x64)
    __shared__ __align__(16) short Gb[4096];      // 8 KB bf16 G swz

    const int b    = blockIdx.x;        // 0..511
    const int tid  = threadIdx.x;       // 0..511
    const int lane = tid & 63;
    const int w    = tid >> 6;          // 0..7
    const int head = b >> 4, ch = b & 15;

    {   // DMA bf16 G image (8 KB, linear; pre-swizzled at write time)
        const short* gg = gbf + (size_t)head * 4096 + w * 512 + lane * 8;
        async_copy16(gg, Gb + w * 512);
    }

    // Reg-stage X tile (128x64 f32), convert, swizzled LDS writes.
    const float* xh = x + ((size_t)head * TDIM + ch * 128) * DDIM;
#pragma unroll
    for (int e = 0; e < 4; ++e) {
        const int i4 = e * 512 + tid;            // f4 index in 128x64 tile
        const int r  = i4 >> 4;                  // 0..127
        const int c4 = (i4 & 15) << 2;
        const f4 v = *reinterpret_cast<const f4*>(xh + (size_t)i4 * 4);
        s4 pk;
        pk[0] = f2bf(v[0]); pk[1] = f2bf(v[1]);
        pk[2] = f2bf(v[2]); pk[3] = f2bf(v[3]);
        *(s4*)((char*)Xb + r * 128 + ((2 * c4) ^ ((r & 7) << 4))) = pk;
    }
    __syncthreads();   // drains G DMA (vmcnt) + Xb writes (lgkmcnt)

    // MFMA: wave w owns rows w*16..w*16+15 x 4 col-tiles, K=64.
    const int li = lane & 15, g = lane >> 4;

    f32x4 acc[4];
#pragma unroll
    for (int d = 0; d < 4; ++d) acc[d] = (f32x4){0.f, 0.f, 0.f, 0.f};

#pragma unroll
    for (int k0 = 0; k0 < 64; k0 += 32) {
        bf16x8 af, bv[4];
        af = *fragp(Xb, w * 16 + li, 64, k0 + 8 * g);
#pragma unroll
        for (int d = 0; d < 4; ++d)
            bv[d] = *fragp(Gb, d * 16 + li, 64, k0 + 8 * g);
#pragma unroll
        for (int d = 0; d < 4; ++d)
            acc[d] = __builtin_amdgcn_mfma_f32_16x16x32_bf16(
                af, bv[d], acc[d], 0, 0, 0);
    }

    float* oh = out + ((size_t)head * TDIM + ch * 128) * DDIM;
#pragma unroll
    for (int d = 0; d < 4; ++d)
#pragma unroll
        for (int q = 0; q < 4; ++q)
            oh[(w * 16 + g * 4 + q) * 64 + d * 16 + li] = acc[d][q];
}

extern "C" void kernel_launch(void* const* d_in, const int* in_sizes, int n_in,
                              void* d_out, int out_size, void* d_ws, size_t ws_size,
                              hipStream_t stream) {
    const float* x = (const float*)d_in[0];
    float* out  = (float*)d_out;
    short* part = (short*)d_ws;                          // 512*8 KB = 4.2 MB
    short* gbf  = part + (size_t)512 * 4096;             // 256 KB

    k1_gram<<<NHEADS * NCH, 512, 0, stream>>>(x, part);
    k2a_reduce<<<128, 256, 0, stream>>>(part, gbf);
    k2b_xg<<<512, 512, 0, stream>>>(x, out, gbf);
}